// Round 2
// baseline (13902.200 us; speedup 1.0000x reference)
//
#include <hip/hip_runtime.h>
#include <hip/hip_bf16.h>
#include <math.h>

// Problem constants
#define D_MODEL 1024
#define NHEAD   16
#define DKH     64
#define FFDIM   4096
#define NLAYER  6
#define BATCH   2
#define SEQ     2048
#define NTOK    (BATCH*SEQ)

typedef __bf16 bf16x8 __attribute__((ext_vector_type(8)));
typedef float  f32x4  __attribute__((ext_vector_type(4)));

static __device__ __forceinline__ float bf2f(unsigned short u) {
    union { unsigned int i; float f; } v; v.i = ((unsigned int)u) << 16; return v.f;
}
static __device__ __forceinline__ unsigned short f2bf(float f) {
    __hip_bfloat16 h = __float2bfloat16(f);
    return *reinterpret_cast<unsigned short*>(&h);
}

// -------------------- dtype detection --------------------
// Low 16 bits of u32 words: bf16-pair data -> valid bf16 exponent band (~100%);
// f32 data -> random mantissa bits (~19% band hit). flag=1 means f32 inputs.
__global__ void detect_dtype(const unsigned int* __restrict__ p, int* __restrict__ flag)
{
    __shared__ int cnt;
    if (threadIdx.x == 0) cnt = 0;
    __syncthreads();
    int c = 0;
    for (int i = threadIdx.x; i < 1024; i += 256) {
        unsigned int e = (p[i] >> 7) & 0xFF;
        if (e >= 0x60 && e <= 0x90) c++;
    }
    atomicAdd(&cnt, c);
    __syncthreads();
    if (threadIdx.x == 0) *flag = (cnt < 512) ? 1 : 0;
}

// -------------------- bias/gain conversion into bf16 arena --------------------
__global__ __launch_bounds__(256) void cvt_params(
    const void* bq, const void* bk, const void* bv, const void* bo,
    const void* b1, const void* b2, const void* g1, const void* be1,
    const void* g2, const void* be2,
    unsigned short* __restrict__ arena, const int* __restrict__ flag)
{
    int i = blockIdx.x * 256 + threadIdx.x;
    if (i >= 79872) return;
    const void* src; int j;
    if      (i < 6144)  { src = bq;  j = i; }
    else if (i < 12288) { src = bk;  j = i - 6144; }
    else if (i < 18432) { src = bv;  j = i - 12288; }
    else if (i < 24576) { src = bo;  j = i - 18432; }
    else if (i < 49152) { src = b1;  j = i - 24576; }
    else if (i < 55296) { src = b2;  j = i - 49152; }
    else if (i < 61440) { src = g1;  j = i - 55296; }
    else if (i < 67584) { src = be1; j = i - 61440; }
    else if (i < 73728) { src = g2;  j = i - 67584; }
    else                { src = be2; j = i - 73728; }
    arena[i] = (*flag) ? f2bf(((const float*)src)[j])
                       : ((const unsigned short*)src)[j];
}

// -------------------- embedding + positional encoding --------------------
__global__ __launch_bounds__(256) void embed_pe(const int* __restrict__ src,
        const void* __restrict__ emb,
        float* __restrict__ xf, unsigned short* __restrict__ xb,
        const int* __restrict__ flag)
{
    int tok = blockIdx.x;
    int b = tok / SEQ;
    int id = src[tok];
    int t = threadIdx.x;
    int d0 = t * 4;
    float ev[4];
    if (*flag) {
        float4 v = *(const float4*)((const float*)emb + (size_t)id * D_MODEL + d0);
        ev[0] = v.x; ev[1] = v.y; ev[2] = v.z; ev[3] = v.w;
    } else {
        ushort4 v = *(const ushort4*)((const unsigned short*)emb + (size_t)id * D_MODEL + d0);
        ev[0] = bf2f(v.x); ev[1] = bf2f(v.y); ev[2] = bf2f(v.z); ev[3] = bf2f(v.w);
    }
    float pos = (float)b;
    float vals[4];
    #pragma unroll
    for (int e = 0; e < 4; e++) {
        int d = d0 + e;
        int deven = d & ~1;
        float div_ = expf((float)deven * (-9.210340371976184f / 1024.0f));
        float ang = pos / div_;
        float pe = (d & 1) ? cosf(ang) : sinf(ang);
        vals[e] = ev[e] + pe;
    }
    float4 f4 = {vals[0], vals[1], vals[2], vals[3]};
    *(float4*)(xf + (size_t)tok * D_MODEL + d0) = f4;
    ushort4 o = {f2bf(vals[0]), f2bf(vals[1]), f2bf(vals[2]), f2bf(vals[3])};
    *(ushort4*)(xb + (size_t)tok * D_MODEL + d0) = o;
}

// -------------------- transpose (any dtype, +element offset) -> bf16 B^T ----
__global__ __launch_bounds__(256) void transpose_any(const void* __restrict__ in,
        size_t elemOff, unsigned short* __restrict__ out, int R, int Cn,
        const int* __restrict__ flag)
{
    __shared__ unsigned short tl[32][33];
    int isf = *flag;
    int c0 = blockIdx.x * 32, r0 = blockIdx.y * 32;
    int tc = threadIdx.x & 31, tr = threadIdx.x >> 5;
    #pragma unroll
    for (int i = 0; i < 4; i++) {
        int r = tr + i * 8;
        size_t idx = elemOff + (size_t)(r0 + r) * Cn + c0 + tc;
        tl[r][tc] = isf ? f2bf(((const float*)in)[idx])
                        : ((const unsigned short*)in)[idx];
    }
    __syncthreads();
    #pragma unroll
    for (int i = 0; i < 4; i++) {
        int r = tr + i * 8;
        out[(size_t)(c0 + r) * R + r0 + tc] = tl[tc][r];
    }
}

// -------------------- bf16 MFMA GEMM: C[M,N] = A[M,K] @ Bt^T + bias ---------
template<int RELU>
__global__ __launch_bounds__(256) void gemm_bt(
        const unsigned short* __restrict__ A,
        const unsigned short* __restrict__ Bt,
        const unsigned short* __restrict__ bias,
        unsigned short* __restrict__ C,
        int M, int N, int K)
{
    __shared__ unsigned short As[128][40];
    __shared__ unsigned short Bs[128][40];
    int tid = threadIdx.x;
    int lane = tid & 63;
    int wave = tid >> 6;
    int bm = blockIdx.x * 128;
    int bn = blockIdx.y * 128;
    int wm = (wave >> 1) * 64;
    int wn = (wave & 1) * 64;
    int l15 = lane & 15;
    int quad = lane >> 4;

    f32x4 acc[4][4] = {};

    int sr = tid >> 2;
    int sc = (tid & 3) * 8;
    const unsigned short* Aptr = A + (size_t)(bm + sr) * K + sc;
    const unsigned short* Bptr = Bt + (size_t)(bn + sr) * K + sc;

    for (int k0 = 0; k0 < K; k0 += 32) {
        int4 a0 = *(const int4*)(Aptr + k0);
        int4 a1 = *(const int4*)(Aptr + (size_t)64 * K + k0);
        int4 b0 = *(const int4*)(Bptr + k0);
        int4 b1 = *(const int4*)(Bptr + (size_t)64 * K + k0);
        *(int4*)&As[sr][sc]      = a0;
        *(int4*)&As[sr + 64][sc] = a1;
        *(int4*)&Bs[sr][sc]      = b0;
        *(int4*)&Bs[sr + 64][sc] = b1;
        __syncthreads();
        bf16x8 af[4], bfr[4];
        #pragma unroll
        for (int i = 0; i < 4; i++)
            af[i] = *(const bf16x8*)&As[wm + i * 16 + l15][quad * 8];
        #pragma unroll
        for (int j = 0; j < 4; j++)
            bfr[j] = *(const bf16x8*)&Bs[wn + j * 16 + l15][quad * 8];
        #pragma unroll
        for (int i = 0; i < 4; i++)
            #pragma unroll
            for (int j = 0; j < 4; j++)
                acc[i][j] = __builtin_amdgcn_mfma_f32_16x16x32_bf16(af[i], bfr[j], acc[i][j], 0, 0, 0);
        __syncthreads();
    }

    #pragma unroll
    for (int i = 0; i < 4; i++) {
        int row0 = bm + wm + i * 16 + quad * 4;
        #pragma unroll
        for (int j = 0; j < 4; j++) {
            int col = bn + wn + j * 16 + l15;
            float bv = bf2f(bias[col]);
            #pragma unroll
            for (int r = 0; r < 4; r++) {
                float v = acc[i][j][r] + bv;
                if (RELU) v = fmaxf(v, 0.0f);
                C[(size_t)(row0 + r) * N + col] = f2bf(v);
            }
        }
    }
}

// -------------------- flash-style attention --------------------
__global__ __launch_bounds__(256) void attn_kernel(
        const unsigned short* __restrict__ q,
        const unsigned short* __restrict__ k,
        const unsigned short* __restrict__ v,
        const int* __restrict__ mask,
        unsigned short* __restrict__ out)
{
    __shared__ float Qs[16][68];
    __shared__ float Ks[64][68];
    __shared__ float Vs[64][68];
    __shared__ float Ss[16][68];
    __shared__ float mrow[16], lrow[16], arow[16];

    int qt = blockIdx.x, h = blockIdx.y, b = blockIdx.z;
    int t = threadIdx.x;
    int s0 = qt * 16;
    int qlo = t >> 4, dbase = (t & 15) * 4;

    {
        const unsigned short* qp = q + ((size_t)(b * SEQ + s0 + qlo) * D_MODEL) + h * DKH + dbase;
        ushort4 qv = *(const ushort4*)qp;
        Qs[qlo][dbase + 0] = bf2f(qv.x) * (1.0f / 32.0f);
        Qs[qlo][dbase + 1] = bf2f(qv.y) * (1.0f / 32.0f);
        Qs[qlo][dbase + 2] = bf2f(qv.z) * (1.0f / 32.0f);
        Qs[qlo][dbase + 3] = bf2f(qv.w) * (1.0f / 32.0f);
    }
    if (t < 16) { mrow[t] = -INFINITY; lrow[t] = 0.0f; }
    float o0 = 0.f, o1 = 0.f, o2 = 0.f, o3 = 0.f;
    __syncthreads();

    for (int kt = 0; kt < SEQ / 64; kt++) {
        {
            int r = t >> 2, cg = (t & 3) * 16;
            const unsigned short* kp = k + ((size_t)(b * SEQ + kt * 64 + r) * D_MODEL) + h * DKH + cg;
            const unsigned short* vp = v + ((size_t)(b * SEQ + kt * 64 + r) * D_MODEL) + h * DKH + cg;
            union { int4 v4; unsigned short s[8]; } u0, u1, u2, u3;
            u0.v4 = *(const int4*)kp;
            u1.v4 = *(const int4*)(kp + 8);
            u2.v4 = *(const int4*)vp;
            u3.v4 = *(const int4*)(vp + 8);
            #pragma unroll
            for (int e = 0; e < 8; e++) {
                Ks[r][cg + e]     = bf2f(u0.s[e]);
                Ks[r][cg + 8 + e] = bf2f(u1.s[e]);
                Vs[r][cg + e]     = bf2f(u2.s[e]);
                Vs[r][cg + 8 + e] = bf2f(u3.s[e]);
            }
        }
        __syncthreads();
        {
            int ql = t >> 4, klb = t & 15;
            #pragma unroll
            for (int kk = 0; kk < 4; kk++) {
                int kc = kk * 16 + klb;
                float s = 0.f;
                #pragma unroll
                for (int d = 0; d < DKH; d += 4) {
                    float4 qv = *(const float4*)&Qs[ql][d];
                    float4 kv = *(const float4*)&Ks[kc][d];
                    s += qv.x * kv.x + qv.y * kv.y + qv.z * kv.z + qv.w * kv.w;
                }
                int kg = kt * 64 + kc;
                if (mask[b * SEQ + kg] == 0) s = -1e9f;
                Ss[ql][kc] = s;
            }
        }
        __syncthreads();
        if (t < 16) {
            float mo = mrow[t], mx = mo;
            for (int kk = 0; kk < 64; kk++) mx = fmaxf(mx, Ss[t][kk]);
            float al = expf(mo - mx);
            float sum = 0.f;
            for (int kk = 0; kk < 64; kk++) {
                float p = expf(Ss[t][kk] - mx);
                Ss[t][kk] = p;
                sum += p;
            }
            lrow[t] = lrow[t] * al + sum;
            mrow[t] = mx;
            arow[t] = al;
        }
        __syncthreads();
        {
            float al = arow[qlo];
            o0 *= al; o1 *= al; o2 *= al; o3 *= al;
            #pragma unroll
            for (int kk = 0; kk < 64; kk += 4) {
                float4 pv = *(const float4*)&Ss[qlo][kk];
                float4 va = *(const float4*)&Vs[kk + 0][dbase];
                float4 vb = *(const float4*)&Vs[kk + 1][dbase];
                float4 vc = *(const float4*)&Vs[kk + 2][dbase];
                float4 vd = *(const float4*)&Vs[kk + 3][dbase];
                o0 += pv.x * va.x + pv.y * vb.x + pv.z * vc.x + pv.w * vd.x;
                o1 += pv.x * va.y + pv.y * vb.y + pv.z * vc.y + pv.w * vd.y;
                o2 += pv.x * va.z + pv.y * vb.z + pv.z * vc.z + pv.w * vd.z;
                o3 += pv.x * va.w + pv.y * vb.w + pv.z * vc.w + pv.w * vd.w;
            }
        }
        __syncthreads();
    }
    float li = 1.0f / lrow[qlo];
    unsigned short* op = out + ((size_t)(b * SEQ + s0 + qlo) * D_MODEL) + h * DKH + dbase;
    ushort4 ov = { f2bf(o0 * li), f2bf(o1 * li), f2bf(o2 * li), f2bf(o3 * li) };
    *(ushort4*)op = ov;
}

// -------------------- fused residual add + LayerNorm --------------------
__global__ __launch_bounds__(256) void add_ln(
        float* __restrict__ xf,
        const unsigned short* __restrict__ delta,
        const unsigned short* __restrict__ g,
        const unsigned short* __restrict__ be,
        unsigned short* __restrict__ xb)
{
    __shared__ float wsum[4], wsum2[4];
    int tok = blockIdx.x;
    int t = threadIdx.x;
    int d0 = t * 4;
    float4 xv = *(float4*)(xf + (size_t)tok * D_MODEL + d0);
    ushort4 dv = *(const ushort4*)(delta + (size_t)tok * D_MODEL + d0);
    float v0 = xv.x + bf2f(dv.x);
    float v1 = xv.y + bf2f(dv.y);
    float v2 = xv.z + bf2f(dv.z);
    float v3 = xv.w + bf2f(dv.w);
    float s = v0 + v1 + v2 + v3;
    float s2 = v0 * v0 + v1 * v1 + v2 * v2 + v3 * v3;
    #pragma unroll
    for (int off = 32; off > 0; off >>= 1) {
        s  += __shfl_down(s, off);
        s2 += __shfl_down(s2, off);
    }
    int wave = t >> 6, lane = t & 63;
    if (lane == 0) { wsum[wave] = s; wsum2[wave] = s2; }
    __syncthreads();
    float tot  = wsum[0] + wsum[1] + wsum[2] + wsum[3];
    float tot2 = wsum2[0] + wsum2[1] + wsum2[2] + wsum2[3];
    float mean = tot * (1.0f / 1024.0f);
    float var  = tot2 * (1.0f / 1024.0f) - mean * mean;
    float rs = rsqrtf(var + 1e-5f);
    ushort4 gv  = *(const ushort4*)(g + d0);
    ushort4 bev = *(const ushort4*)(be + d0);
    float y0 = (v0 - mean) * rs * bf2f(gv.x) + bf2f(bev.x);
    float y1 = (v1 - mean) * rs * bf2f(gv.y) + bf2f(bev.y);
    float y2 = (v2 - mean) * rs * bf2f(gv.z) + bf2f(bev.z);
    float y3 = (v3 - mean) * rs * bf2f(gv.w) + bf2f(bev.w);
    float4 yo = {y0, y1, y2, y3};
    *(float4*)(xf + (size_t)tok * D_MODEL + d0) = yo;
    ushort4 ob = {f2bf(y0), f2bf(y1), f2bf(y2), f2bf(y3)};
    *(ushort4*)(xb + (size_t)tok * D_MODEL + d0) = ob;
}

// -------------------- output store (dtype per flag) --------------------
__global__ __launch_bounds__(256) void copy_out_any(const float* __restrict__ xf,
        void* __restrict__ out, const int* __restrict__ flag)
{
    int i = blockIdx.x * 1024 + threadIdx.x * 4;
    float4 vv = *(const float4*)(xf + i);
    if (*flag) {
        *(float4*)((float*)out + i) = vv;
    } else {
        ushort4 o = {f2bf(vv.x), f2bf(vv.y), f2bf(vv.z), f2bf(vv.w)};
        *(ushort4*)((unsigned short*)out + i) = o;
    }
}

// -------------------- host side --------------------
extern "C" void kernel_launch(void* const* d_in, const int* in_sizes, int n_in,
                              void* d_out, int out_size, void* d_ws, size_t ws_size,
                              hipStream_t stream)
{
    const int* src  = (const int*)d_in[0];
    const int* mask = (const int*)d_in[1];
    const void* emb = d_in[2];
    const void* Wq  = d_in[3];
    const void* bq  = d_in[4];
    const void* Wk  = d_in[5];
    const void* bk  = d_in[6];
    const void* Wv  = d_in[7];
    const void* bv  = d_in[8];
    const void* Wo  = d_in[9];
    const void* bo  = d_in[10];
    const void* W1  = d_in[11];
    const void* b1  = d_in[12];
    const void* W2  = d_in[13];
    const void* b2  = d_in[14];
    const void* g1  = d_in[15];
    const void* be1 = d_in[16];
    const void* g2  = d_in[17];
    const void* be2 = d_in[18];

    char* wsb = (char*)d_ws;
    size_t off = 0;
    auto alloc = [&](size_t bytes) -> void* {
        void* p = wsb + off;
        off += (bytes + 255) & ~(size_t)255;
        return p;
    };
    float* xf           = (float*)alloc((size_t)NTOK * D_MODEL * 4);
    unsigned short* xb  = (unsigned short*)alloc((size_t)NTOK * D_MODEL * 2);
    unsigned short* qb  = (unsigned short*)alloc((size_t)NTOK * D_MODEL * 2);
    unsigned short* kb  = (unsigned short*)alloc((size_t)NTOK * D_MODEL * 2);
    unsigned short* vb  = (unsigned short*)alloc((size_t)NTOK * D_MODEL * 2);
    unsigned short* ao  = (unsigned short*)alloc((size_t)NTOK * D_MODEL * 2);
    unsigned short* ffb = (unsigned short*)alloc((size_t)NTOK * FFDIM * 2);
    unsigned short* wT  = (unsigned short*)alloc((size_t)D_MODEL * FFDIM * 2);
    unsigned short* arena = (unsigned short*)alloc(79872 * 2);
    int* flag           = (int*)alloc(256);
    unsigned short* tmp = qb;  // qb dead after attention; reuse for deltas
    (void)ws_size; (void)in_sizes; (void)n_in; (void)out_size;

    const int szD = NLAYER * D_MODEL;
    const unsigned short* c_bq  = arena;
    const unsigned short* c_bk  = arena + szD;
    const unsigned short* c_bv  = arena + 2 * szD;
    const unsigned short* c_bo  = arena + 3 * szD;
    const unsigned short* c_b1  = arena + 4 * szD;
    const unsigned short* c_b2  = arena + 4 * szD + NLAYER * FFDIM;
    const unsigned short* c_g1  = arena + 5 * szD + NLAYER * FFDIM;
    const unsigned short* c_be1 = arena + 6 * szD + NLAYER * FFDIM;
    const unsigned short* c_g2  = arena + 7 * szD + NLAYER * FFDIM;
    const unsigned short* c_be2 = arena + 8 * szD + NLAYER * FFDIM;

    detect_dtype<<<1, 256, 0, stream>>>((const unsigned int*)emb, flag);
    cvt_params<<<312, 256, 0, stream>>>(bq, bk, bv, bo, b1, b2, g1, be1, g2, be2, arena, flag);
    embed_pe<<<NTOK, 256, 0, stream>>>(src, emb, xf, xb, flag);

    for (int l = 0; l < NLAYER; l++) {
        size_t offDD = (size_t)l * D_MODEL * D_MODEL;
        size_t offDF = (size_t)l * D_MODEL * FFDIM;
        const unsigned short* bq_l = c_bq + (size_t)l * D_MODEL;
        const unsigned short* bk_l = c_bk + (size_t)l * D_MODEL;
        const unsigned short* bv_l = c_bv + (size_t)l * D_MODEL;
        const unsigned short* bo_l = c_bo + (size_t)l * D_MODEL;
        const unsigned short* b1_l = c_b1 + (size_t)l * FFDIM;
        const unsigned short* b2_l = c_b2 + (size_t)l * D_MODEL;

        transpose_any<<<dim3(32, 32), 256, 0, stream>>>(Wq, offDD, wT, D_MODEL, D_MODEL, flag);
        gemm_bt<0><<<dim3(32, 8), 256, 0, stream>>>(xb, wT, bq_l, qb, NTOK, D_MODEL, D_MODEL);
        transpose_any<<<dim3(32, 32), 256, 0, stream>>>(Wk, offDD, wT, D_MODEL, D_MODEL, flag);
        gemm_bt<0><<<dim3(32, 8), 256, 0, stream>>>(xb, wT, bk_l, kb, NTOK, D_MODEL, D_MODEL);
        transpose_any<<<dim3(32, 32), 256, 0, stream>>>(Wv, offDD, wT, D_MODEL, D_MODEL, flag);
        gemm_bt<0><<<dim3(32, 8), 256, 0, stream>>>(xb, wT, bv_l, vb, NTOK, D_MODEL, D_MODEL);

        attn_kernel<<<dim3(SEQ / 16, NHEAD, BATCH), 256, 0, stream>>>(qb, kb, vb, mask, ao);

        transpose_any<<<dim3(32, 32), 256, 0, stream>>>(Wo, offDD, wT, D_MODEL, D_MODEL, flag);
        gemm_bt<0><<<dim3(32, 8), 256, 0, stream>>>(ao, wT, bo_l, tmp, NTOK, D_MODEL, D_MODEL);
        add_ln<<<NTOK, 256, 0, stream>>>(xf, tmp, c_g1 + (size_t)l * D_MODEL, c_be1 + (size_t)l * D_MODEL, xb);

        transpose_any<<<dim3(128, 32), 256, 0, stream>>>(W1, offDF, wT, D_MODEL, FFDIM, flag);
        gemm_bt<1><<<dim3(32, 32), 256, 0, stream>>>(xb, wT, b1_l, ffb, NTOK, FFDIM, D_MODEL);
        transpose_any<<<dim3(32, 128), 256, 0, stream>>>(W2, offDF, wT, FFDIM, D_MODEL, flag);
        gemm_bt<0><<<dim3(32, 8), 256, 0, stream>>>(ffb, wT, b2_l, tmp, NTOK, D_MODEL, FFDIM);
        add_ln<<<NTOK, 256, 0, stream>>>(xf, tmp, c_g2 + (size_t)l * D_MODEL, c_be2 + (size_t)l * D_MODEL, xb);
    }

    copy_out_any<<<NTOK, 256, 0, stream>>>(xf, d_out, flag);
}

// Round 3
// 3024.455 us; speedup vs baseline: 4.5966x; 4.5966x over previous
//
#include <hip/hip_runtime.h>
#include <hip/hip_bf16.h>
#include <math.h>

// Problem constants
#define D_MODEL 1024
#define NHEAD   16
#define DKH     64
#define FFDIM   4096
#define NLAYER  6
#define BATCH   2
#define SEQ     2048
#define NTOK    (BATCH*SEQ)

typedef __bf16 bf16x8 __attribute__((ext_vector_type(8)));
typedef float  f32x4  __attribute__((ext_vector_type(4)));

static __device__ __forceinline__ float bf2f(unsigned short u) {
    union { unsigned int i; float f; } v; v.i = ((unsigned int)u) << 16; return v.f;
}
static __device__ __forceinline__ unsigned short f2bf(float f) {
    __hip_bfloat16 h = __float2bfloat16(f);
    return *reinterpret_cast<unsigned short*>(&h);
}

// -------------------- dtype detection --------------------
__global__ void detect_dtype(const unsigned int* __restrict__ p, int* __restrict__ flag)
{
    __shared__ int cnt;
    if (threadIdx.x == 0) cnt = 0;
    __syncthreads();
    int c = 0;
    for (int i = threadIdx.x; i < 1024; i += 256) {
        unsigned int e = (p[i] >> 7) & 0xFF;
        if (e >= 0x60 && e <= 0x90) c++;
    }
    atomicAdd(&cnt, c);
    __syncthreads();
    if (threadIdx.x == 0) *flag = (cnt < 512) ? 1 : 0;
}

// -------------------- bias/gain conversion into bf16 arena --------------------
__global__ __launch_bounds__(256) void cvt_params(
    const void* bq, const void* bk, const void* bv, const void* bo,
    const void* b1, const void* b2, const void* g1, const void* be1,
    const void* g2, const void* be2,
    unsigned short* __restrict__ arena, const int* __restrict__ flag)
{
    int i = blockIdx.x * 256 + threadIdx.x;
    if (i >= 79872) return;
    const void* src; int j;
    if      (i < 6144)  { src = bq;  j = i; }
    else if (i < 12288) { src = bk;  j = i - 6144; }
    else if (i < 18432) { src = bv;  j = i - 12288; }
    else if (i < 24576) { src = bo;  j = i - 18432; }
    else if (i < 49152) { src = b1;  j = i - 24576; }
    else if (i < 55296) { src = b2;  j = i - 49152; }
    else if (i < 61440) { src = g1;  j = i - 55296; }
    else if (i < 67584) { src = be1; j = i - 61440; }
    else if (i < 73728) { src = g2;  j = i - 67584; }
    else                { src = be2; j = i - 73728; }
    arena[i] = (*flag) ? f2bf(((const float*)src)[j])
                       : ((const unsigned short*)src)[j];
}

// -------------------- embedding + positional encoding --------------------
__global__ __launch_bounds__(256) void embed_pe(const int* __restrict__ src,
        const void* __restrict__ emb,
        float* __restrict__ xf, unsigned short* __restrict__ xb,
        const int* __restrict__ flag)
{
    int tok = blockIdx.x;
    int b = tok / SEQ;
    int id = src[tok];
    int t = threadIdx.x;
    int d0 = t * 4;
    float ev[4];
    if (*flag) {
        float4 v = *(const float4*)((const float*)emb + (size_t)id * D_MODEL + d0);
        ev[0] = v.x; ev[1] = v.y; ev[2] = v.z; ev[3] = v.w;
    } else {
        ushort4 v = *(const ushort4*)((const unsigned short*)emb + (size_t)id * D_MODEL + d0);
        ev[0] = bf2f(v.x); ev[1] = bf2f(v.y); ev[2] = bf2f(v.z); ev[3] = bf2f(v.w);
    }
    float pos = (float)b;
    float vals[4];
    #pragma unroll
    for (int e = 0; e < 4; e++) {
        int d = d0 + e;
        int deven = d & ~1;
        float div_ = expf((float)deven * (-9.210340371976184f / 1024.0f));
        float ang = pos / div_;
        float pe = (d & 1) ? cosf(ang) : sinf(ang);
        vals[e] = ev[e] + pe;
    }
    float4 f4 = {vals[0], vals[1], vals[2], vals[3]};
    *(float4*)(xf + (size_t)tok * D_MODEL + d0) = f4;
    ushort4 o = {f2bf(vals[0]), f2bf(vals[1]), f2bf(vals[2]), f2bf(vals[3])};
    *(ushort4*)(xb + (size_t)tok * D_MODEL + d0) = o;
}

// -------------------- transpose (any dtype, +element offset) -> bf16 B^T ----
__global__ __launch_bounds__(256) void transpose_any(const void* __restrict__ in,
        size_t elemOff, unsigned short* __restrict__ out, int R, int Cn,
        const int* __restrict__ flag)
{
    __shared__ unsigned short tl[32][33];
    int isf = *flag;
    int c0 = blockIdx.x * 32, r0 = blockIdx.y * 32;
    int tc = threadIdx.x & 31, tr = threadIdx.x >> 5;
    #pragma unroll
    for (int i = 0; i < 4; i++) {
        int r = tr + i * 8;
        size_t idx = elemOff + (size_t)(r0 + r) * Cn + c0 + tc;
        tl[r][tc] = isf ? f2bf(((const float*)in)[idx])
                        : ((const unsigned short*)in)[idx];
    }
    __syncthreads();
    #pragma unroll
    for (int i = 0; i < 4; i++) {
        int r = tr + i * 8;
        out[(size_t)(c0 + r) * R + r0 + tc] = tl[tc][r];
    }
}

// -------------------- V transpose: vb[B*S,1024] -> vtb[B,H,64,S] -------------
__global__ __launch_bounds__(256) void transpose_v(const unsigned short* __restrict__ vb,
        unsigned short* __restrict__ vtb)
{
    __shared__ unsigned short tl[32][33];
    int s0 = blockIdx.x * 32, c0 = blockIdx.y * 32, b = blockIdx.z;
    int tc = threadIdx.x & 31, tr = threadIdx.x >> 5;
    #pragma unroll
    for (int i = 0; i < 4; i++) {
        int r = tr + i * 8;
        tl[r][tc] = vb[(size_t)(b * SEQ + s0 + r) * D_MODEL + c0 + tc];
    }
    __syncthreads();
    #pragma unroll
    for (int i = 0; i < 4; i++) {
        int r = tr + i * 8;        // r indexes d within this 32-col strip
        int dglob = c0 + r;
        int h = dglob >> 6, dd = dglob & 63;
        vtb[((size_t)(b * NHEAD + h) * DKH + dd) * SEQ + s0 + tc] = tl[tc][r];
    }
}

// -------------------- bf16 MFMA GEMM: C[M,N] = A[M,K] @ Bt^T + bias ---------
template<int RELU>
__global__ __launch_bounds__(256) void gemm_bt(
        const unsigned short* __restrict__ A,
        const unsigned short* __restrict__ Bt,
        const unsigned short* __restrict__ bias,
        unsigned short* __restrict__ C,
        int M, int N, int K)
{
    __shared__ unsigned short As[128][40];
    __shared__ unsigned short Bs[128][40];
    int tid = threadIdx.x;
    int lane = tid & 63;
    int wave = tid >> 6;
    int bm = blockIdx.x * 128;
    int bn = blockIdx.y * 128;
    int wm = (wave >> 1) * 64;
    int wn = (wave & 1) * 64;
    int l15 = lane & 15;
    int quad = lane >> 4;

    f32x4 acc[4][4] = {};

    int sr = tid >> 2;
    int sc = (tid & 3) * 8;
    const unsigned short* Aptr = A + (size_t)(bm + sr) * K + sc;
    const unsigned short* Bptr = Bt + (size_t)(bn + sr) * K + sc;

    for (int k0 = 0; k0 < K; k0 += 32) {
        int4 a0 = *(const int4*)(Aptr + k0);
        int4 a1 = *(const int4*)(Aptr + (size_t)64 * K + k0);
        int4 b0 = *(const int4*)(Bptr + k0);
        int4 b1 = *(const int4*)(Bptr + (size_t)64 * K + k0);
        *(int4*)&As[sr][sc]      = a0;
        *(int4*)&As[sr + 64][sc] = a1;
        *(int4*)&Bs[sr][sc]      = b0;
        *(int4*)&Bs[sr + 64][sc] = b1;
        __syncthreads();
        bf16x8 af[4], bfr[4];
        #pragma unroll
        for (int i = 0; i < 4; i++)
            af[i] = *(const bf16x8*)&As[wm + i * 16 + l15][quad * 8];
        #pragma unroll
        for (int j = 0; j < 4; j++)
            bfr[j] = *(const bf16x8*)&Bs[wn + j * 16 + l15][quad * 8];
        #pragma unroll
        for (int i = 0; i < 4; i++)
            #pragma unroll
            for (int j = 0; j < 4; j++)
                acc[i][j] = __builtin_amdgcn_mfma_f32_16x16x32_bf16(af[i], bfr[j], acc[i][j], 0, 0, 0);
        __syncthreads();
    }

    #pragma unroll
    for (int i = 0; i < 4; i++) {
        int row0 = bm + wm + i * 16 + quad * 4;
        #pragma unroll
        for (int j = 0; j < 4; j++) {
            int col = bn + wn + j * 16 + l15;
            float bv = bf2f(bias[col]);
            #pragma unroll
            for (int r = 0; r < 4; r++) {
                float v = acc[i][j][r] + bv;
                if (RELU) v = fmaxf(v, 0.0f);
                C[(size_t)(row0 + r) * N + col] = f2bf(v);
            }
        }
    }
}

// -------------------- MFMA flash attention --------------------
// Block: 256 thr (4 waves), Q-tile 128 (32 q/wave), K-tile 64, head dim 64.
// S = Q.K^T via mfma (A=Q rows contig-in-d, B=K rows contig-in-d, no transposes).
// Online softmax in registers (C-layout row = quad*4+r, col = lane&15;
// row reductions via __shfl_xor width 16 inside each quad group).
// P -> LDS (bf16, verified C->A layout round trip), PV uses pre-transposed V.
// scale = 1/sqrt(D_MODEL) = 1/32 (reference quirk).
__global__ __launch_bounds__(256) void attn_mfma(
        const unsigned short* __restrict__ q,
        const unsigned short* __restrict__ k,
        const unsigned short* __restrict__ vtb,   // [B,H,64,SEQ]
        const int* __restrict__ mask,
        unsigned short* __restrict__ out)
{
    __shared__ unsigned short Ks[64][72];
    __shared__ unsigned short Vt[64][72];
    __shared__ unsigned short Ps[128][72];

    int qt = blockIdx.x, h = blockIdx.y, b = blockIdx.z;
    int t = threadIdx.x, lane = t & 63, wave = t >> 6;
    int l15 = lane & 15, quad = lane >> 4;
    int q0 = qt * 128;
    int wq = wave * 32;

    // Q fragments: 2 m-tiles x 2 k-chunks, resident all kernel
    bf16x8 qf[2][2];
    #pragma unroll
    for (int im = 0; im < 2; im++)
        #pragma unroll
        for (int kc = 0; kc < 2; kc++)
            qf[im][kc] = *(const bf16x8*)(q +
                ((size_t)(b * SEQ + q0 + wq + im * 16 + l15)) * D_MODEL +
                h * DKH + kc * 32 + quad * 8);

    f32x4 oacc[2][4] = {};
    float mrow[2][4], lrow[2][4];
    #pragma unroll
    for (int im = 0; im < 2; im++)
        #pragma unroll
        for (int r = 0; r < 4; r++) { mrow[im][r] = -INFINITY; lrow[im][r] = 0.0f; }

    const unsigned short* kbase_p = k + (size_t)b * SEQ * D_MODEL + h * DKH;
    const unsigned short* vbase_p = vtb + (size_t)(b * NHEAD + h) * DKH * SEQ;

    for (int kb = 0; kb < SEQ; kb += 64) {
        // stage K tile (rows: key, cols: d) and Vt tile (rows: d, cols: key)
        #pragma unroll
        for (int c = t; c < 512; c += 256) {
            int r = c >> 3, o = (c & 7) * 8;
            *(int4*)&Ks[r][o] = *(const int4*)(kbase_p + (size_t)(kb + r) * D_MODEL + o);
            *(int4*)&Vt[r][o] = *(const int4*)(vbase_p + (size_t)r * SEQ + kb + o);
        }
        __syncthreads();

        #pragma unroll
        for (int im = 0; im < 2; im++) {
            // scores: 16q x 64k strip
            f32x4 s[4];
            #pragma unroll
            for (int jn = 0; jn < 4; jn++) {
                f32x4 a = {0.f, 0.f, 0.f, 0.f};
                #pragma unroll
                for (int kc = 0; kc < 2; kc++) {
                    bf16x8 kf = *(const bf16x8*)&Ks[jn * 16 + l15][kc * 32 + quad * 8];
                    a = __builtin_amdgcn_mfma_f32_16x16x32_bf16(qf[im][kc], kf, a, 0, 0, 0);
                }
                int mv = mask[b * SEQ + kb + jn * 16 + l15];
                #pragma unroll
                for (int r = 0; r < 4; r++)
                    a[r] = mv ? a[r] * (1.0f / 32.0f) : -1e9f;
                s[jn] = a;
            }
            // row max (local over jn, then across 16 cols in quad group)
            f32x4 mx = s[0];
            #pragma unroll
            for (int jn = 1; jn < 4; jn++)
                #pragma unroll
                for (int r = 0; r < 4; r++) mx[r] = fmaxf(mx[r], s[jn][r]);
            #pragma unroll
            for (int d = 1; d < 16; d <<= 1)
                #pragma unroll
                for (int r = 0; r < 4; r++)
                    mx[r] = fmaxf(mx[r], __shfl_xor(mx[r], d, 16));
            float alpha[4], mnew[4];
            #pragma unroll
            for (int r = 0; r < 4; r++) {
                mnew[r] = fmaxf(mrow[im][r], mx[r]);
                alpha[r] = __expf(mrow[im][r] - mnew[r]);
                mrow[im][r] = mnew[r];
            }
            // p = exp(s - mnew), row sums, write P to LDS
            f32x4 sum = {0.f, 0.f, 0.f, 0.f};
            #pragma unroll
            for (int jn = 0; jn < 4; jn++) {
                #pragma unroll
                for (int r = 0; r < 4; r++) {
                    float p = __expf(s[jn][r] - mnew[r]);
                    sum[r] += p;
                    Ps[wq + im * 16 + quad * 4 + r][jn * 16 + l15] = f2bf(p);
                }
            }
            #pragma unroll
            for (int d = 1; d < 16; d <<= 1)
                #pragma unroll
                for (int r = 0; r < 4; r++)
                    sum[r] += __shfl_xor(sum[r], d, 16);
            #pragma unroll
            for (int r = 0; r < 4; r++)
                lrow[im][r] = lrow[im][r] * alpha[r] + sum[r];
            // rescale O accumulators
            #pragma unroll
            for (int jd = 0; jd < 4; jd++)
                #pragma unroll
                for (int r = 0; r < 4; r++)
                    oacc[im][jd][r] *= alpha[r];
        }
        __syncthreads();
        // O += P @ V
        #pragma unroll
        for (int im = 0; im < 2; im++)
            #pragma unroll
            for (int jd = 0; jd < 4; jd++)
                #pragma unroll
                for (int kc = 0; kc < 2; kc++) {
                    bf16x8 pf = *(const bf16x8*)&Ps[wq + im * 16 + l15][kc * 32 + quad * 8];
                    bf16x8 vf = *(const bf16x8*)&Vt[jd * 16 + l15][kc * 32 + quad * 8];
                    oacc[im][jd] = __builtin_amdgcn_mfma_f32_16x16x32_bf16(pf, vf, oacc[im][jd], 0, 0, 0);
                }
        __syncthreads();
    }

    // epilogue: O / l
    #pragma unroll
    for (int im = 0; im < 2; im++) {
        float inv[4];
        #pragma unroll
        for (int r = 0; r < 4; r++) inv[r] = 1.0f / lrow[im][r];
        #pragma unroll
        for (int jd = 0; jd < 4; jd++) {
            #pragma unroll
            for (int r = 0; r < 4; r++) {
                int row = b * SEQ + q0 + wq + im * 16 + quad * 4 + r;
                int col = h * DKH + jd * 16 + l15;
                out[(size_t)row * D_MODEL + col] = f2bf(oacc[im][jd][r] * inv[r]);
            }
        }
    }
}

// -------------------- fused residual add + LayerNorm --------------------
__global__ __launch_bounds__(256) void add_ln(
        float* __restrict__ xf,
        const unsigned short* __restrict__ delta,
        const unsigned short* __restrict__ g,
        const unsigned short* __restrict__ be,
        unsigned short* __restrict__ xb)
{
    __shared__ float wsum[4], wsum2[4];
    int tok = blockIdx.x;
    int t = threadIdx.x;
    int d0 = t * 4;
    float4 xv = *(float4*)(xf + (size_t)tok * D_MODEL + d0);
    ushort4 dv = *(const ushort4*)(delta + (size_t)tok * D_MODEL + d0);
    float v0 = xv.x + bf2f(dv.x);
    float v1 = xv.y + bf2f(dv.y);
    float v2 = xv.z + bf2f(dv.z);
    float v3 = xv.w + bf2f(dv.w);
    float s = v0 + v1 + v2 + v3;
    float s2 = v0 * v0 + v1 * v1 + v2 * v2 + v3 * v3;
    #pragma unroll
    for (int off = 32; off > 0; off >>= 1) {
        s  += __shfl_down(s, off);
        s2 += __shfl_down(s2, off);
    }
    int wave = t >> 6, lane = t & 63;
    if (lane == 0) { wsum[wave] = s; wsum2[wave] = s2; }
    __syncthreads();
    float tot  = wsum[0] + wsum[1] + wsum[2] + wsum[3];
    float tot2 = wsum2[0] + wsum2[1] + wsum2[2] + wsum2[3];
    float mean = tot * (1.0f / 1024.0f);
    float var  = tot2 * (1.0f / 1024.0f) - mean * mean;
    float rs = rsqrtf(var + 1e-5f);
    ushort4 gv  = *(const ushort4*)(g + d0);
    ushort4 bev = *(const ushort4*)(be + d0);
    float y0 = (v0 - mean) * rs * bf2f(gv.x) + bf2f(bev.x);
    float y1 = (v1 - mean) * rs * bf2f(gv.y) + bf2f(bev.y);
    float y2 = (v2 - mean) * rs * bf2f(gv.z) + bf2f(bev.z);
    float y3 = (v3 - mean) * rs * bf2f(gv.w) + bf2f(bev.w);
    float4 yo = {y0, y1, y2, y3};
    *(float4*)(xf + (size_t)tok * D_MODEL + d0) = yo;
    ushort4 ob = {f2bf(y0), f2bf(y1), f2bf(y2), f2bf(y3)};
    *(ushort4*)(xb + (size_t)tok * D_MODEL + d0) = ob;
}

// -------------------- output store (dtype per flag) --------------------
__global__ __launch_bounds__(256) void copy_out_any(const float* __restrict__ xf,
        void* __restrict__ out, const int* __restrict__ flag)
{
    int i = blockIdx.x * 1024 + threadIdx.x * 4;
    float4 vv = *(const float4*)(xf + i);
    if (*flag) {
        *(float4*)((float*)out + i) = vv;
    } else {
        ushort4 o = {f2bf(vv.x), f2bf(vv.y), f2bf(vv.z), f2bf(vv.w)};
        *(ushort4*)((unsigned short*)out + i) = o;
    }
}

// -------------------- host side --------------------
extern "C" void kernel_launch(void* const* d_in, const int* in_sizes, int n_in,
                              void* d_out, int out_size, void* d_ws, size_t ws_size,
                              hipStream_t stream)
{
    const int* src  = (const int*)d_in[0];
    const int* mask = (const int*)d_in[1];
    const void* emb = d_in[2];
    const void* Wq  = d_in[3];
    const void* bq  = d_in[4];
    const void* Wk  = d_in[5];
    const void* bk  = d_in[6];
    const void* Wv  = d_in[7];
    const void* bv  = d_in[8];
    const void* Wo  = d_in[9];
    const void* bo  = d_in[10];
    const void* W1  = d_in[11];
    const void* b1  = d_in[12];
    const void* W2  = d_in[13];
    const void* b2  = d_in[14];
    const void* g1  = d_in[15];
    const void* be1 = d_in[16];
    const void* g2  = d_in[17];
    const void* be2 = d_in[18];

    char* wsb = (char*)d_ws;
    size_t off = 0;
    auto alloc = [&](size_t bytes) -> void* {
        void* p = wsb + off;
        off += (bytes + 255) & ~(size_t)255;
        return p;
    };
    float* xf           = (float*)alloc((size_t)NTOK * D_MODEL * 4);
    unsigned short* xb  = (unsigned short*)alloc((size_t)NTOK * D_MODEL * 2);
    unsigned short* qb  = (unsigned short*)alloc((size_t)NTOK * D_MODEL * 2);
    unsigned short* kb  = (unsigned short*)alloc((size_t)NTOK * D_MODEL * 2);
    unsigned short* vb  = (unsigned short*)alloc((size_t)NTOK * D_MODEL * 2);
    unsigned short* ao  = (unsigned short*)alloc((size_t)NTOK * D_MODEL * 2);
    unsigned short* ffb = (unsigned short*)alloc((size_t)NTOK * FFDIM * 2);
    unsigned short* wT  = (unsigned short*)alloc((size_t)D_MODEL * FFDIM * 2);
    unsigned short* arena = (unsigned short*)alloc(79872 * 2);
    int* flag           = (int*)alloc(256);
    unsigned short* tmp = qb;   // qb dead after attention; reuse for deltas
    unsigned short* vtb = ffb;  // ffb dead during attention; holds V^T [B,H,64,S]
    (void)ws_size; (void)in_sizes; (void)n_in; (void)out_size;

    const int szD = NLAYER * D_MODEL;
    const unsigned short* c_bq  = arena;
    const unsigned short* c_bk  = arena + szD;
    const unsigned short* c_bv  = arena + 2 * szD;
    const unsigned short* c_bo  = arena + 3 * szD;
    const unsigned short* c_b1  = arena + 4 * szD;
    const unsigned short* c_b2  = arena + 4 * szD + NLAYER * FFDIM;
    const unsigned short* c_g1  = arena + 5 * szD + NLAYER * FFDIM;
    const unsigned short* c_be1 = arena + 6 * szD + NLAYER * FFDIM;
    const unsigned short* c_g2  = arena + 7 * szD + NLAYER * FFDIM;
    const unsigned short* c_be2 = arena + 8 * szD + NLAYER * FFDIM;

    detect_dtype<<<1, 256, 0, stream>>>((const unsigned int*)emb, flag);
    cvt_params<<<312, 256, 0, stream>>>(bq, bk, bv, bo, b1, b2, g1, be1, g2, be2, arena, flag);
    embed_pe<<<NTOK, 256, 0, stream>>>(src, emb, xf, xb, flag);

    for (int l = 0; l < NLAYER; l++) {
        size_t offDD = (size_t)l * D_MODEL * D_MODEL;
        size_t offDF = (size_t)l * D_MODEL * FFDIM;
        const unsigned short* bq_l = c_bq + (size_t)l * D_MODEL;
        const unsigned short* bk_l = c_bk + (size_t)l * D_MODEL;
        const unsigned short* bv_l = c_bv + (size_t)l * D_MODEL;
        const unsigned short* bo_l = c_bo + (size_t)l * D_MODEL;
        const unsigned short* b1_l = c_b1 + (size_t)l * FFDIM;
        const unsigned short* b2_l = c_b2 + (size_t)l * D_MODEL;

        transpose_any<<<dim3(32, 32), 256, 0, stream>>>(Wq, offDD, wT, D_MODEL, D_MODEL, flag);
        gemm_bt<0><<<dim3(32, 8), 256, 0, stream>>>(xb, wT, bq_l, qb, NTOK, D_MODEL, D_MODEL);
        transpose_any<<<dim3(32, 32), 256, 0, stream>>>(Wk, offDD, wT, D_MODEL, D_MODEL, flag);
        gemm_bt<0><<<dim3(32, 8), 256, 0, stream>>>(xb, wT, bk_l, kb, NTOK, D_MODEL, D_MODEL);
        transpose_any<<<dim3(32, 32), 256, 0, stream>>>(Wv, offDD, wT, D_MODEL, D_MODEL, flag);
        gemm_bt<0><<<dim3(32, 8), 256, 0, stream>>>(xb, wT, bv_l, vb, NTOK, D_MODEL, D_MODEL);

        transpose_v<<<dim3(SEQ / 32, D_MODEL / 32, BATCH), 256, 0, stream>>>(vb, vtb);
        attn_mfma<<<dim3(SEQ / 128, NHEAD, BATCH), 256, 0, stream>>>(qb, kb, vtb, mask, ao);

        transpose_any<<<dim3(32, 32), 256, 0, stream>>>(Wo, offDD, wT, D_MODEL, D_MODEL, flag);
        gemm_bt<0><<<dim3(32, 8), 256, 0, stream>>>(ao, wT, bo_l, tmp, NTOK, D_MODEL, D_MODEL);
        add_ln<<<NTOK, 256, 0, stream>>>(xf, tmp, c_g1 + (size_t)l * D_MODEL, c_be1 + (size_t)l * D_MODEL, xb);

        transpose_any<<<dim3(128, 32), 256, 0, stream>>>(W1, offDF, wT, D_MODEL, FFDIM, flag);
        gemm_bt<1><<<dim3(32, 32), 256, 0, stream>>>(xb, wT, b1_l, ffb, NTOK, FFDIM, D_MODEL);
        transpose_any<<<dim3(32, 128), 256, 0, stream>>>(W2, offDF, wT, FFDIM, D_MODEL, flag);
        gemm_bt<0><<<dim3(32, 8), 256, 0, stream>>>(ffb, wT, b2_l, tmp, NTOK, D_MODEL, FFDIM);
        add_ln<<<NTOK, 256, 0, stream>>>(xf, tmp, c_g2 + (size_t)l * D_MODEL, c_be2 + (size_t)l * D_MODEL, xb);
    }

    copy_out_any<<<NTOK, 256, 0, stream>>>(xf, d_out, flag);
}